// Round 1
// baseline (74.463 us; speedup 1.0000x reference)
//
#include <hip/hip_runtime.h>

// Causal depthwise conv1d, K=4, over x:(B,T,D) fp32, D contiguous.
// y[b,t,d] = sum_j x[b,t-3+j,d]*w[d,j] + bias[d]
//
// Each thread owns 4 consecutive channels (one float4 along D) and slides a
// 4-deep register window across TC time steps. Loads/stores are float4,
// coalesced across the wave (lanes cover consecutive d).

#define TC 32  // time steps per block; halo amplification (TC+3)/TC = 1.09

__global__ __launch_bounds__(256) void shortconv_kernel(
    const float* __restrict__ x, const float* __restrict__ w,
    const float* __restrict__ bias, float* __restrict__ out,
    int T, int D4)
{
    const int d4 = blockIdx.x * blockDim.x + threadIdx.x;  // float4 index along D
    const int t0 = blockIdx.y * TC;
    const int b  = blockIdx.z;

    const float4* __restrict__ x4 = reinterpret_cast<const float4*>(x);
    float4* __restrict__ o4       = reinterpret_cast<float4*>(out);
    const float4* __restrict__ w4 = reinterpret_cast<const float4*>(w);
    const float4* __restrict__ b4 = reinterpret_cast<const float4*>(bias);

    // weight layout: (D,1,4) flat = w[d*4 + j]. For channels d4*4 .. d4*4+3,
    // w4[d4*4 + i] = the 4 taps of channel (d4*4 + i).
    const float4 w0 = w4[d4 * 4 + 0];
    const float4 w1 = w4[d4 * 4 + 1];
    const float4 w2 = w4[d4 * 4 + 2];
    const float4 w3 = w4[d4 * 4 + 3];
    const float4 bz = b4[d4];

    const long rowbase = (long)b * T;  // in rows
    const float4 zero = make_float4(0.f, 0.f, 0.f, 0.f);

    float4 xm3 = (t0 - 3 >= 0) ? x4[(rowbase + t0 - 3) * D4 + d4] : zero;
    float4 xm2 = (t0 - 2 >= 0) ? x4[(rowbase + t0 - 2) * D4 + d4] : zero;
    float4 xm1 = (t0 - 1 >= 0) ? x4[(rowbase + t0 - 1) * D4 + d4] : zero;

    #pragma unroll
    for (int i = 0; i < TC; ++i) {
        const long r = rowbase + t0 + i;
        const float4 xc = x4[r * D4 + d4];
        float4 y;
        y.x = xm3.x * w0.x + xm2.x * w0.y + xm1.x * w0.z + xc.x * w0.w + bz.x;
        y.y = xm3.y * w1.x + xm2.y * w1.y + xm1.y * w1.z + xc.y * w1.w + bz.y;
        y.z = xm3.z * w2.x + xm2.z * w2.y + xm1.z * w2.z + xc.z * w2.w + bz.z;
        y.w = xm3.w * w3.x + xm2.w * w3.y + xm1.w * w3.z + xc.w * w3.w + bz.w;
        o4[r * D4 + d4] = y;
        xm3 = xm2; xm2 = xm1; xm1 = xc;
    }
}

extern "C" void kernel_launch(void* const* d_in, const int* in_sizes, int n_in,
                              void* d_out, int out_size, void* d_ws, size_t ws_size,
                              hipStream_t stream) {
    const float* x    = (const float*)d_in[0];
    const float* w    = (const float*)d_in[1];
    const float* bias = (const float*)d_in[2];
    float* out        = (float*)d_out;

    const int D = 2048;
    const int B = 4;
    const int T = in_sizes[0] / (B * D);  // 4096
    const int D4 = D / 4;                 // 512

    dim3 block(256);
    dim3 grid(D4 / 256, T / TC, B);       // (2, 128, 4)
    shortconv_kernel<<<grid, block, 0, stream>>>(x, w, bias, out, T, D4);
}

// Round 3
// 50.448 us; speedup vs baseline: 1.4760x; 1.4760x over previous
//
#include <hip/hip_runtime.h>

// Causal depthwise conv1d, K=4, over x:(B,T,D) fp32, D contiguous.
// y[b,t,d] = sum_j x[b,t-3+j,d]*w[d,j] + bias[d]
//
// Each thread owns 4 consecutive channels (one fx4 along D) and slides a
// 4-deep register window across TC time steps. Loads/stores are 16B,
// coalesced across the wave (lanes cover consecutive d).
//
// TC=8: small per-thread register footprint -> higher occupancy, 4096 blocks
// -> latency hiding + short drain tail. Halo rows are L2/L3 hits (shared with
// time-adjacent block). Nontemporal stores keep the write stream from
// evicting x out of L3. Uses clang ext_vector_type (native vector) because
// __builtin_nontemporal_store rejects HIP_vector_type float4.

typedef float fx4 __attribute__((ext_vector_type(4)));

#define TC 8

__global__ __launch_bounds__(256) void shortconv_kernel(
    const float* __restrict__ x, const float* __restrict__ w,
    const float* __restrict__ bias, float* __restrict__ out,
    int T, int D4)
{
    const int d4 = blockIdx.x * blockDim.x + threadIdx.x;  // fx4 index along D
    const int t0 = blockIdx.y * TC;
    const int b  = blockIdx.z;

    const fx4* __restrict__ x4 = reinterpret_cast<const fx4*>(x);
    fx4* __restrict__ o4       = reinterpret_cast<fx4*>(out);
    const fx4* __restrict__ w4 = reinterpret_cast<const fx4*>(w);
    const fx4* __restrict__ b4 = reinterpret_cast<const fx4*>(bias);

    // weight layout: (D,1,4) flat = w[d*4 + j]. For channels d4*4 .. d4*4+3,
    // w4[d4*4 + i] = the 4 taps of channel (d4*4 + i).
    const fx4 w0 = w4[d4 * 4 + 0];
    const fx4 w1 = w4[d4 * 4 + 1];
    const fx4 w2 = w4[d4 * 4 + 2];
    const fx4 w3 = w4[d4 * 4 + 3];
    const fx4 bz = b4[d4];

    const long rowbase = (long)b * T;  // in rows
    const fx4 zero = (fx4)0.0f;

    fx4 xm3 = (t0 - 3 >= 0) ? x4[(rowbase + t0 - 3) * D4 + d4] : zero;
    fx4 xm2 = (t0 - 2 >= 0) ? x4[(rowbase + t0 - 2) * D4 + d4] : zero;
    fx4 xm1 = (t0 - 1 >= 0) ? x4[(rowbase + t0 - 1) * D4 + d4] : zero;

    #pragma unroll
    for (int i = 0; i < TC; ++i) {
        const long r = rowbase + t0 + i;
        const fx4 xc = x4[r * D4 + d4];
        fx4 y;
        y.x = xm3.x * w0.x + xm2.x * w0.y + xm1.x * w0.z + xc.x * w0.w + bz.x;
        y.y = xm3.y * w1.x + xm2.y * w1.y + xm1.y * w1.z + xc.y * w1.w + bz.y;
        y.z = xm3.z * w2.x + xm2.z * w2.y + xm1.z * w2.z + xc.z * w2.w + bz.z;
        y.w = xm3.w * w3.x + xm2.w * w3.y + xm1.w * w3.z + xc.w * w3.w + bz.w;
        __builtin_nontemporal_store(y, &o4[r * D4 + d4]);
        xm3 = xm2; xm2 = xm1; xm1 = xc;
    }
}

extern "C" void kernel_launch(void* const* d_in, const int* in_sizes, int n_in,
                              void* d_out, int out_size, void* d_ws, size_t ws_size,
                              hipStream_t stream) {
    const float* x    = (const float*)d_in[0];
    const float* w    = (const float*)d_in[1];
    const float* bias = (const float*)d_in[2];
    float* out        = (float*)d_out;

    const int D = 2048;
    const int B = 4;
    const int T = in_sizes[0] / (B * D);  // 4096
    const int D4 = D / 4;                 // 512

    dim3 block(256);
    dim3 grid(D4 / 256, T / TC, B);       // (2, 512, 4) = 4096 blocks
    shortconv_kernel<<<grid, block, 0, stream>>>(x, w, bias, out, T, D4);
}

// Round 4
// 49.913 us; speedup vs baseline: 1.4919x; 1.0107x over previous
//
#include <hip/hip_runtime.h>

// Causal depthwise conv1d, K=4, x:(B=4, T=4096, D=2048) fp32, D contiguous.
// y[b,t,d] = sum_j x[b,t-3+j,d]*w[d,j] + bias[d]
//
// Each thread owns 4 consecutive channels (one fx4 along D). Per block-row it
// BATCH-loads all TC+3 rows (halo + body) into registers first -- 11
// independent global_load_dwordx4 in flight per thread (MLP), -- then
// computes and nontemporal-stores the TC outputs. NT stores keep the write
// stream from evicting x out of the 256 MiB L3 (x is L3-resident across
// replays). T/D hardcoded so addressing is base + constant.

typedef float fx4 __attribute__((ext_vector_type(4)));

#define TC 8
#define T_CONST 4096
#define D4_CONST 512

__global__ __launch_bounds__(256) void shortconv_kernel(
    const float* __restrict__ x, const float* __restrict__ w,
    const float* __restrict__ bias, float* __restrict__ out)
{
    const int d4 = blockIdx.x * 256 + threadIdx.x;   // fx4 index along D
    const int t0 = blockIdx.y * TC;
    const int b  = blockIdx.z;

    const fx4* __restrict__ x4 = reinterpret_cast<const fx4*>(x);
    fx4* __restrict__ o4       = reinterpret_cast<fx4*>(out);
    const fx4* __restrict__ w4 = reinterpret_cast<const fx4*>(w);
    const fx4* __restrict__ b4 = reinterpret_cast<const fx4*>(bias);

    const long rowbase = (long)b * T_CONST + t0;      // in rows
    const fx4* __restrict__ xp = x4 + rowbase * D4_CONST + d4;  // row t0, this thread's column
    fx4* __restrict__ op       = o4 + rowbase * D4_CONST + d4;

    const fx4 zero = (fx4)0.0f;

    // ---- batch load: rows t0-3 .. t0+TC-1 ----
    fx4 xr[TC + 3];
    if (t0 >= 3) {
        #pragma unroll
        for (int i = 0; i < TC + 3; ++i)
            xr[i] = xp[(long)(i - 3) * D4_CONST];
    } else {  // t0 == 0 (TC >= 3 so only the first block-row pads)
        xr[0] = zero; xr[1] = zero; xr[2] = zero;
        #pragma unroll
        for (int i = 3; i < TC + 3; ++i)
            xr[i] = xp[(long)(i - 3) * D4_CONST];
    }

    // weight layout: (D,1,4) flat = w[d*4 + j]; w4[d4*4+i] = taps of channel d4*4+i.
    const fx4 w0 = w4[d4 * 4 + 0];
    const fx4 w1 = w4[d4 * 4 + 1];
    const fx4 w2 = w4[d4 * 4 + 2];
    const fx4 w3 = w4[d4 * 4 + 3];
    const fx4 bz = b4[d4];

    // ---- compute + NT store ----
    #pragma unroll
    for (int i = 0; i < TC; ++i) {
        const fx4 a = xr[i], bb = xr[i + 1], c = xr[i + 2], e = xr[i + 3];
        fx4 y;
        y.x = a.x * w0.x + bb.x * w0.y + c.x * w0.z + e.x * w0.w + bz.x;
        y.y = a.y * w1.x + bb.y * w1.y + c.y * w1.z + e.y * w1.w + bz.y;
        y.z = a.z * w2.x + bb.z * w2.y + c.z * w2.z + e.z * w2.w + bz.z;
        y.w = a.w * w3.x + bb.w * w3.y + c.w * w3.z + e.w * w3.w + bz.w;
        __builtin_nontemporal_store(y, &op[(long)i * D4_CONST]);
    }
}

extern "C" void kernel_launch(void* const* d_in, const int* in_sizes, int n_in,
                              void* d_out, int out_size, void* d_ws, size_t ws_size,
                              hipStream_t stream) {
    const float* x    = (const float*)d_in[0];
    const float* w    = (const float*)d_in[1];
    const float* bias = (const float*)d_in[2];
    float* out        = (float*)d_out;

    dim3 block(256);
    dim3 grid(D4_CONST / 256, T_CONST / TC, 4);   // (2, 512, 4) = 4096 blocks
    shortconv_kernel<<<grid, block, 0, stream>>>(x, w, bias, out);
}

// Round 5
// 47.698 us; speedup vs baseline: 1.5611x; 1.0464x over previous
//
#include <hip/hip_runtime.h>

// Causal depthwise conv1d, K=4, x:(B=4, T=4096, D=2048) fp32, D contiguous.
// y[b,t,d] = sum_j x[b,t-3+j,d]*w[d,j] + bias[d]
//
// Each thread owns 4 consecutive channels (one fx4 along D). Per block it
// batch-loads all TC+3 rows (halo + body) into registers (19 independent
// global_load_dwordx4 in flight), then computes and nontemporal-stores the
// TC outputs. NT stores keep the write stream from write-allocating (round-2
// lesson: WRITE_SIZE 219MB -> 131MB exact).
//
// TC=16 (was 8): halo amplification 1.375 -> 1.19, ~30% fewer VMEM
// instructions per byte. VGPR ~110 -> 4 waves/SIMD = 16 waves/CU; with 19
// loads in flight each that's ~300 outstanding loads/CU — latency covered.

typedef float fx4 __attribute__((ext_vector_type(4)));

#define TC 16
#define T_CONST 4096
#define D4_CONST 512

__global__ __launch_bounds__(256) void shortconv_kernel(
    const float* __restrict__ x, const float* __restrict__ w,
    const float* __restrict__ bias, float* __restrict__ out)
{
    const int d4 = blockIdx.x * 256 + threadIdx.x;   // fx4 index along D
    const int t0 = blockIdx.y * TC;
    const int b  = blockIdx.z;

    const fx4* __restrict__ x4 = reinterpret_cast<const fx4*>(x);
    fx4* __restrict__ o4       = reinterpret_cast<fx4*>(out);
    const fx4* __restrict__ w4 = reinterpret_cast<const fx4*>(w);
    const fx4* __restrict__ b4 = reinterpret_cast<const fx4*>(bias);

    const long rowbase = (long)b * T_CONST + t0;      // in rows
    const fx4* __restrict__ xp = x4 + rowbase * D4_CONST + d4;  // row t0, this column
    fx4* __restrict__ op       = o4 + rowbase * D4_CONST + d4;

    const fx4 zero = (fx4)0.0f;

    // ---- batch load: rows t0-3 .. t0+TC-1 ----
    fx4 xr[TC + 3];
    if (t0 >= 3) {
        #pragma unroll
        for (int i = 0; i < TC + 3; ++i)
            xr[i] = xp[(long)(i - 3) * D4_CONST];
    } else {  // t0 == 0 block only
        xr[0] = zero; xr[1] = zero; xr[2] = zero;
        #pragma unroll
        for (int i = 3; i < TC + 3; ++i)
            xr[i] = xp[(long)(i - 3) * D4_CONST];
    }

    // weight layout: (D,1,4) flat = w[d*4 + j]; w4[d4*4+i] = taps of channel d4*4+i.
    const fx4 w0 = w4[d4 * 4 + 0];
    const fx4 w1 = w4[d4 * 4 + 1];
    const fx4 w2 = w4[d4 * 4 + 2];
    const fx4 w3 = w4[d4 * 4 + 3];
    const fx4 bz = b4[d4];

    // ---- compute + NT store ----
    #pragma unroll
    for (int i = 0; i < TC; ++i) {
        const fx4 a = xr[i], bb = xr[i + 1], c = xr[i + 2], e = xr[i + 3];
        fx4 y;
        y.x = a.x * w0.x + bb.x * w0.y + c.x * w0.z + e.x * w0.w + bz.x;
        y.y = a.y * w1.x + bb.y * w1.y + c.y * w1.z + e.y * w1.w + bz.y;
        y.z = a.z * w2.x + bb.z * w2.y + c.z * w2.z + e.z * w2.w + bz.z;
        y.w = a.w * w3.x + bb.w * w3.y + c.w * w3.z + e.w * w3.w + bz.w;
        __builtin_nontemporal_store(y, &op[(long)i * D4_CONST]);
    }
}

extern "C" void kernel_launch(void* const* d_in, const int* in_sizes, int n_in,
                              void* d_out, int out_size, void* d_ws, size_t ws_size,
                              hipStream_t stream) {
    const float* x    = (const float*)d_in[0];
    const float* w    = (const float*)d_in[1];
    const float* bias = (const float*)d_in[2];
    float* out        = (float*)d_out;

    dim3 block(256);
    dim3 grid(D4_CONST / 256, T_CONST / TC, 4);   // (2, 256, 4) = 2048 blocks
    shortconv_kernel<<<grid, block, 0, stream>>>(x, w, bias, out);
}

// Round 6
// 47.221 us; speedup vs baseline: 1.5769x; 1.0101x over previous
//
#include <hip/hip_runtime.h>

// Causal depthwise conv1d, K=4, x:(B=4, T=4096, D=2048) fp32, D contiguous.
// y[b,t,d] = sum_j x[b,t-3+j,d]*w[d,j] + bias[d]
//
// Each thread owns 4 consecutive channels (one fx4 along D). Per block it
// batch-loads all TC+3 rows (halo + body) into registers, then computes and
// nontemporal-stores the TC outputs (NT: WRITE_SIZE stays 131MB exact, no
// write-allocate).
//
// Round-5 lesson: without a fence the compiler sinks the batch loads back
// into the compute loop (VGPR fell to 36 -> only ~5 outstanding loads/wave
// -> 2.5KB in flight/CU vs the ~5KB needed to cover HBM latency at 6.3TB/s).
// sched_barrier(0) after the load loop pins all 19 loads before compute:
// VGPR ~90-100, 5 waves/SIMD, ~380 loads (~6KB) in flight per CU.

typedef float fx4 __attribute__((ext_vector_type(4)));

#define TC 16
#define T_CONST 4096
#define D4_CONST 512

__global__ __launch_bounds__(256) void shortconv_kernel(
    const float* __restrict__ x, const float* __restrict__ w,
    const float* __restrict__ bias, float* __restrict__ out)
{
    const int d4 = blockIdx.x * 256 + threadIdx.x;   // fx4 index along D
    const int t0 = blockIdx.y * TC;
    const int b  = blockIdx.z;

    const fx4* __restrict__ x4 = reinterpret_cast<const fx4*>(x);
    fx4* __restrict__ o4       = reinterpret_cast<fx4*>(out);
    const fx4* __restrict__ w4 = reinterpret_cast<const fx4*>(w);
    const fx4* __restrict__ b4 = reinterpret_cast<const fx4*>(bias);

    const long rowbase = (long)b * T_CONST + t0;      // in rows
    const fx4* __restrict__ xp = x4 + rowbase * D4_CONST + d4;  // row t0, this column
    fx4* __restrict__ op       = o4 + rowbase * D4_CONST + d4;

    const fx4 zero = (fx4)0.0f;

    // weight layout: (D,1,4) flat = w[d*4 + j]; w4[d4*4+i] = taps of channel d4*4+i.
    const fx4 w0 = w4[d4 * 4 + 0];
    const fx4 w1 = w4[d4 * 4 + 1];
    const fx4 w2 = w4[d4 * 4 + 2];
    const fx4 w3 = w4[d4 * 4 + 3];
    const fx4 bz = b4[d4];

    // ---- batch load: rows t0-3 .. t0+TC-1, all issued before any compute ----
    fx4 xr[TC + 3];
    if (t0 >= 3) {
        #pragma unroll
        for (int i = 0; i < TC + 3; ++i)
            xr[i] = xp[(long)(i - 3) * D4_CONST];
    } else {  // t0 == 0 block only
        xr[0] = zero; xr[1] = zero; xr[2] = zero;
        #pragma unroll
        for (int i = 3; i < TC + 3; ++i)
            xr[i] = xp[(long)(i - 3) * D4_CONST];
    }
    // Pin: no load may be sunk past this point (keeps 19 loads in flight).
    __builtin_amdgcn_sched_barrier(0);

    // ---- compute + NT store ----
    #pragma unroll
    for (int i = 0; i < TC; ++i) {
        const fx4 a = xr[i], bb = xr[i + 1], c = xr[i + 2], e = xr[i + 3];
        fx4 y;
        y.x = a.x * w0.x + bb.x * w0.y + c.x * w0.z + e.x * w0.w + bz.x;
        y.y = a.y * w1.x + bb.y * w1.y + c.y * w1.z + e.y * w1.w + bz.y;
        y.z = a.z * w2.x + bb.z * w2.y + c.z * w2.z + e.z * w2.w + bz.z;
        y.w = a.w * w3.x + bb.w * w3.y + c.w * w3.z + e.w * w3.w + bz.w;
        __builtin_nontemporal_store(y, &op[(long)i * D4_CONST]);
    }
}

extern "C" void kernel_launch(void* const* d_in, const int* in_sizes, int n_in,
                              void* d_out, int out_size, void* d_ws, size_t ws_size,
                              hipStream_t stream) {
    const float* x    = (const float*)d_in[0];
    const float* w    = (const float*)d_in[1];
    const float* bias = (const float*)d_in[2];
    float* out        = (float*)d_out;

    dim3 block(256);
    dim3 grid(D4_CONST / 256, T_CONST / TC, 4);   // (2, 256, 4) = 2048 blocks
    shortconv_kernel<<<grid, block, 0, stream>>>(x, w, bias, out);
}

// Round 7
// 42.795 us; speedup vs baseline: 1.7400x; 1.1034x over previous
//
#include <hip/hip_runtime.h>

// Causal depthwise conv1d, K=4, x:(B=4, T=4096, D=2048) fp32, D contiguous.
// y[b,t,d] = sum_j x[b,t-3+j,d]*w[d,j] + bias[d]
//
// Structure (settled over rounds 1-6):
//  - thread owns one fx4 (4 channels); wave = 1KB/row, block(256) = 4KB/row
//  - TC=16 rows per block; batch-load 19 rows -> compute -> NT-store 16
//  - NT stores: WRITE_SIZE exact 131MB (round-2: write-allocate cost 65%)
//  - sched_barrier keeps loads hoisted (round-6: VGPR 52, 8 waves/SIMD)
//
// Round-7 change: XCD-bijective block swizzle. Linear workgroup IDs
// round-robin the 8 XCDs, so T-adjacent blocks (which share the 3-row halo)
// landed on different XCDs -> halo fetched twice from L3/HBM. Remap so each
// XCD owns one (d-half, batch) combo and its full contiguous T-range: halo
// becomes a same-XCD L2 hit and each XCD streams a contiguous 16MB x-slab.
//   id in [0,2048): xcd = id&7 -> combo (d_half = xcd&1, b = xcd>>1),
//                   pos = id>>3 -> t_blk. Bijective since 2048 % 8 == 0.

typedef float fx4 __attribute__((ext_vector_type(4)));

#define TC 16
#define T_CONST 4096
#define D4_CONST 512

__global__ __launch_bounds__(256) void shortconv_kernel(
    const float* __restrict__ x, const float* __restrict__ w,
    const float* __restrict__ bias, float* __restrict__ out)
{
    // XCD-aware decomposition of the 1-D block index.
    const int id   = blockIdx.x;        // 0..2047
    const int xcd  = id & 7;            // which XCD this block lands on
    const int pos  = id >> 3;           // 0..255 within the XCD
    const int dh   = xcd & 1;           // d-half owned by this XCD
    const int b    = xcd >> 1;          // batch owned by this XCD
    const int t0   = pos * TC;          // contiguous T-walk within the XCD

    const int d4 = dh * 256 + threadIdx.x;   // fx4 index along D

    const fx4* __restrict__ x4 = reinterpret_cast<const fx4*>(x);
    fx4* __restrict__ o4       = reinterpret_cast<fx4*>(out);
    const fx4* __restrict__ w4 = reinterpret_cast<const fx4*>(w);
    const fx4* __restrict__ b4 = reinterpret_cast<const fx4*>(bias);

    const long rowbase = (long)b * T_CONST + t0;      // in rows
    const fx4* __restrict__ xp = x4 + rowbase * D4_CONST + d4;  // row t0, this column
    fx4* __restrict__ op       = o4 + rowbase * D4_CONST + d4;

    const fx4 zero = (fx4)0.0f;

    // weight layout: (D,1,4) flat = w[d*4 + j]; w4[d4*4+i] = taps of channel d4*4+i.
    const fx4 w0 = w4[d4 * 4 + 0];
    const fx4 w1 = w4[d4 * 4 + 1];
    const fx4 w2 = w4[d4 * 4 + 2];
    const fx4 w3 = w4[d4 * 4 + 3];
    const fx4 bz = b4[d4];

    // ---- batch load: rows t0-3 .. t0+TC-1, issued before compute ----
    fx4 xr[TC + 3];
    if (t0 >= 3) {
        #pragma unroll
        for (int i = 0; i < TC + 3; ++i)
            xr[i] = xp[(long)(i - 3) * D4_CONST];
    } else {  // t0 == 0 block only
        xr[0] = zero; xr[1] = zero; xr[2] = zero;
        #pragma unroll
        for (int i = 3; i < TC + 3; ++i)
            xr[i] = xp[(long)(i - 3) * D4_CONST];
    }
    __builtin_amdgcn_sched_barrier(0);  // don't sink loads into compute

    // ---- compute + NT store ----
    #pragma unroll
    for (int i = 0; i < TC; ++i) {
        const fx4 a = xr[i], bb = xr[i + 1], c = xr[i + 2], e = xr[i + 3];
        fx4 y;
        y.x = a.x * w0.x + bb.x * w0.y + c.x * w0.z + e.x * w0.w + bz.x;
        y.y = a.y * w1.x + bb.y * w1.y + c.y * w1.z + e.y * w1.w + bz.y;
        y.z = a.z * w2.x + bb.z * w2.y + c.z * w2.z + e.z * w2.w + bz.z;
        y.w = a.w * w3.x + bb.w * w3.y + c.w * w3.z + e.w * w3.w + bz.w;
        __builtin_nontemporal_store(y, &op[(long)i * D4_CONST]);
    }
}

extern "C" void kernel_launch(void* const* d_in, const int* in_sizes, int n_in,
                              void* d_out, int out_size, void* d_ws, size_t ws_size,
                              hipStream_t stream) {
    const float* x    = (const float*)d_in[0];
    const float* w    = (const float*)d_in[1];
    const float* bias = (const float*)d_in[2];
    float* out        = (float*)d_out;

    dim3 block(256);
    dim3 grid(2048);   // 1-D; decomposed XCD-aware in the kernel
    shortconv_kernel<<<grid, block, 0, stream>>>(x, w, bias, out);
}